// Round 3
// baseline (3762.588 us; speedup 1.0000x reference)
//
#include <hip/hip_runtime.h>

#define N_NODES 100000
#define N_EDGES 3200000
#define D 128
#define NBUCKETS 782          // ceil(100000 / 128)
#define BCAP 5120             // mean 4093, sigma 64 -> +16 sigma margin

__device__ __forceinline__ float bf2f(unsigned short u) {
  return __uint_as_float(((unsigned)u) << 16);
}
__device__ __forceinline__ unsigned short f2bf(float f) {
  unsigned u = __float_as_uint(f);
  u += 0x7FFF + ((u >> 16) & 1);   // round-to-nearest-even
  return (unsigned short)(u >> 16);
}

// Detect whether edge_index arrived as int64 (odd int32 words all zero) or int32.
__global__ void detect_kernel(const int* __restrict__ ei32, int* __restrict__ flag) {
  __shared__ int anynz;
  if (threadIdx.x == 0) anynz = 0;
  __syncthreads();
  int v = 0;
  for (int i = threadIdx.x; i < 2048; i += 256) v |= ei32[2 * i + 1];
  if (v) atomicOr(&anynz, 1);
  __syncthreads();
  if (threadIdx.x == 0) *flag = (anynz == 0) ? 1 : 0;
}

__global__ void zero_kernel(int* __restrict__ p, int n) {
  int i = blockIdx.x * blockDim.x + threadIdx.x;
  if (i < n) p[i] = 0;
}

// One pass: per-destination degree count + binning into 782 buckets of 128 nodes.
// Entry = (r & 127) << 17 | c   (24 bits used). Appends are address-sequential
// per bucket -> cachelines fill completely (vs the old fill_kernel's 195MB of
// partial-line scatter).
__global__ void bin_kernel(const void* __restrict__ edges, const int* __restrict__ flag,
                           int* __restrict__ cnt, int* __restrict__ bcur,
                           unsigned int* __restrict__ buckets) {
  const bool is64 = (*flag != 0);
  int stride = gridDim.x * blockDim.x;
  for (int e = blockIdx.x * blockDim.x + threadIdx.x; e < N_EDGES; e += stride) {
    int r, c;
    if (is64) {
      r = (int)((const long long*)edges)[e];
      c = (int)((const long long*)edges)[N_EDGES + e];
    } else {
      r = ((const int*)edges)[e];
      c = ((const int*)edges)[N_EDGES + e];
    }
    atomicAdd(&cnt[r], 1);
    int b = r >> 7;
    int pos = atomicAdd(&bcur[b], 1);
    if (pos < BCAP) buckets[(size_t)b * BCAP + pos] = ((unsigned)(r & 127) << 17) | (unsigned)c;
  }
}

__global__ void dinv_kernel(const int* __restrict__ cnt, float* __restrict__ dinv) {
  int i = blockIdx.x * blockDim.x + threadIdx.x;
  if (i < N_NODES) dinv[i] = rsqrtf((float)(cnt[i] + 1));  // +1 self-loop
}

// y[n][d] = bf16( dinv[n] * (x @ W)[n][d] )
__global__ __launch_bounds__(256) void gemm_kernel(const float* __restrict__ x,
                                                   const float* __restrict__ W,
                                                   const float* __restrict__ dinv,
                                                   unsigned short* __restrict__ y) {
  __shared__ float xs[32][132];   // [row][k], padded
  __shared__ float ws[32][128];   // [k][col] chunk
  int tid = threadIdx.x;
  int row0 = blockIdx.x * 32;
#pragma unroll
  for (int i = 0; i < 4; i++) {
    int idx = tid + i * 256;
    int m = idx >> 5, c4 = (idx & 31) << 2;
    *(float4*)&xs[m][c4] = *(const float4*)(x + (size_t)(row0 + m) * D + c4);
  }
  float acc[4][4] = {};
  int tx = tid & 31, ty = tid >> 5;  // cols tx*4.., rows ty*4..
  for (int k0 = 0; k0 < 128; k0 += 32) {
#pragma unroll
    for (int i = 0; i < 4; i++) {
      int idx = tid + i * 256;
      int kk = idx >> 5, c4 = (idx & 31) << 2;
      *(float4*)&ws[kk][c4] = *(const float4*)(W + (size_t)(k0 + kk) * D + c4);
    }
    __syncthreads();
#pragma unroll
    for (int k = 0; k < 32; k += 4) {
      float4 a0 = *(float4*)&xs[ty * 4 + 0][k0 + k];
      float4 a1 = *(float4*)&xs[ty * 4 + 1][k0 + k];
      float4 a2 = *(float4*)&xs[ty * 4 + 2][k0 + k];
      float4 a3 = *(float4*)&xs[ty * 4 + 3][k0 + k];
      float4 w0 = *(float4*)&ws[k + 0][tx * 4];
      float4 w1 = *(float4*)&ws[k + 1][tx * 4];
      float4 w2 = *(float4*)&ws[k + 2][tx * 4];
      float4 w3 = *(float4*)&ws[k + 3][tx * 4];
#define ROWFMA(i, ai)                                              \
      acc[i][0] += ai.x * w0.x + ai.y * w1.x + ai.z * w2.x + ai.w * w3.x; \
      acc[i][1] += ai.x * w0.y + ai.y * w1.y + ai.z * w2.y + ai.w * w3.y; \
      acc[i][2] += ai.x * w0.z + ai.y * w1.z + ai.z * w2.z + ai.w * w3.z; \
      acc[i][3] += ai.x * w0.w + ai.y * w1.w + ai.z * w2.w + ai.w * w3.w;
      ROWFMA(0, a0)
      ROWFMA(1, a1)
      ROWFMA(2, a2)
      ROWFMA(3, a3)
#undef ROWFMA
    }
    __syncthreads();
  }
#pragma unroll
  for (int i = 0; i < 4; i++) {
    int row = row0 + ty * 4 + i;
    float di = dinv[row];
    unsigned short h0 = f2bf(di * acc[i][0]);
    unsigned short h1 = f2bf(di * acc[i][1]);
    unsigned short h2 = f2bf(di * acc[i][2]);
    unsigned short h3 = f2bf(di * acc[i][3]);
    uint2 pk;
    pk.x = (unsigned)h0 | ((unsigned)h1 << 16);
    pk.y = (unsigned)h2 | ((unsigned)h3 << 16);
    *(uint2*)(y + (size_t)row * D + tx * 4) = pk;
  }
}

// One block per bucket (128 nodes). LDS accumulator acc[128][128] f32.
// Lane l owns feature dims l and l+64 -> ds_add at bank l%32 (2-way alias, free).
__global__ __launch_bounds__(1024) void agg_ln_kernel(
    const unsigned short* __restrict__ y, const unsigned int* __restrict__ buckets,
    const int* __restrict__ bcur, const float* __restrict__ dinv,
    const float* __restrict__ bias, const float* __restrict__ gamma,
    const float* __restrict__ beta, float* __restrict__ out) {
  __shared__ float acc[128][128];  // 64 KB
  int b = blockIdx.x;
  int tid = threadIdx.x, wid = tid >> 6, lane = tid & 63;

  // zero LDS: 1024 threads x 4 float4 = 4096 float4 = 16384 floats
  float4 z = {0.f, 0.f, 0.f, 0.f};
#pragma unroll
  for (int i = 0; i < 4; i++) ((float4*)acc)[tid + i * 1024] = z;
  __syncthreads();

  int m = bcur[b];
  if (m > BCAP) m = BCAP;
  const unsigned int* bk = buckets + (size_t)b * BCAP;

  for (int base = wid * 64; base < m; base += 1024) {
    int have = m - base;
    if (have > 64) have = 64;
    unsigned int ent = (base + lane < m) ? bk[base + lane] : 0u;
    int t = 0;
    for (; t + 1 < have; t += 2) {  // 2 edges in flight
      unsigned int e0 = __shfl(ent, t);
      unsigned int e1 = __shfl(ent, t + 1);
      int c0 = e0 & 0x1FFFF, r0 = e0 >> 17;
      int c1 = e1 & 0x1FFFF, r1 = e1 >> 17;
      float v00 = bf2f(y[(size_t)c0 * D + lane]);
      float v01 = bf2f(y[(size_t)c0 * D + lane + 64]);
      float v10 = bf2f(y[(size_t)c1 * D + lane]);
      float v11 = bf2f(y[(size_t)c1 * D + lane + 64]);
      atomicAdd(&acc[r0][lane], v00);
      atomicAdd(&acc[r0][lane + 64], v01);
      atomicAdd(&acc[r1][lane], v10);
      atomicAdd(&acc[r1][lane + 64], v11);
    }
    if (t < have) {
      unsigned int e0 = __shfl(ent, t);
      int c0 = e0 & 0x1FFFF, r0 = e0 >> 17;
      atomicAdd(&acc[r0][lane], bf2f(y[(size_t)c0 * D + lane]));
      atomicAdd(&acc[r0][lane + 64], bf2f(y[(size_t)c0 * D + lane + 64]));
    }
  }
  __syncthreads();

  // epilogue: 128 nodes / 16 waves = 8 nodes per wave
  float bias_l = bias[lane], bias_h = bias[lane + 64];
  float gam_l = gamma[lane], gam_h = gamma[lane + 64];
  float bet_l = beta[lane], bet_h = beta[lane + 64];
#pragma unroll
  for (int i = 0; i < 8; i++) {
    int nl = wid * 8 + i;
    int node = b * 128 + nl;
    if (node >= N_NODES) break;
    float a0 = acc[nl][lane];
    float a1 = acc[nl][lane + 64];
    // self-loop term
    a0 += bf2f(y[(size_t)node * D + lane]);
    a1 += bf2f(y[(size_t)node * D + lane + 64]);
    float di = dinv[node];
    float v0 = fmaf(di, a0, bias_l);
    float v1 = fmaf(di, a1, bias_h);
    float sum = v0 + v1;
#pragma unroll
    for (int msk = 1; msk <= 32; msk <<= 1) sum += __shfl_xor(sum, msk);
    float mu = sum * (1.0f / 128.0f);
    float d0 = v0 - mu, d1 = v1 - mu;
    float sq = d0 * d0 + d1 * d1;
#pragma unroll
    for (int msk = 1; msk <= 32; msk <<= 1) sq += __shfl_xor(sq, msk);
    float rstd = rsqrtf(sq * (1.0f / 128.0f) + 1e-5f);
    float h0 = fmaxf(fmaf(d0 * rstd, gam_l, bet_l), 0.0f);
    float h1 = fmaxf(fmaf(d1 * rstd, gam_h, bet_h), 0.0f);
    out[(size_t)node * D + lane] = h0;
    out[(size_t)node * D + lane + 64] = h1;
  }
}

extern "C" void kernel_launch(void* const* d_in, const int* in_sizes, int n_in,
                              void* d_out, int out_size, void* d_ws, size_t ws_size,
                              hipStream_t stream) {
  const float* x = (const float*)d_in[0];
  const void* edges = d_in[1];
  const float* W = (const float*)d_in[2];
  const float* b = (const float*)d_in[3];
  const float* gamma = (const float*)d_in[4];
  const float* beta = (const float*)d_in[5];
  float* out = (float*)d_out;

  char* w = (char*)d_ws;
  size_t off = 0;
  auto take = [&](size_t bytes) {
    size_t r = off;
    off += (bytes + 255) & ~(size_t)255;
    return r;
  };
  int* flag = (int*)(w + take(256));
  int* cnt = (int*)(w + take((size_t)(N_NODES + NBUCKETS + 64) * 4));  // cnt + bcur contiguous
  int* bcur = cnt + N_NODES;
  float* dinv = (float*)(w + take((size_t)N_NODES * 4));
  unsigned int* buckets = (unsigned int*)(w + take((size_t)NBUCKETS * BCAP * 4));
  unsigned short* y = (unsigned short*)(w + take((size_t)N_NODES * D * 2));

  detect_kernel<<<1, 256, 0, stream>>>((const int*)edges, flag);
  zero_kernel<<<(N_NODES + NBUCKETS + 255) / 256, 256, 0, stream>>>(cnt, N_NODES + NBUCKETS);
  bin_kernel<<<2048, 256, 0, stream>>>(edges, flag, cnt, bcur, buckets);
  dinv_kernel<<<(N_NODES + 255) / 256, 256, 0, stream>>>(cnt, dinv);
  gemm_kernel<<<N_NODES / 32, 256, 0, stream>>>(x, W, dinv, y);
  agg_ln_kernel<<<NBUCKETS, 1024, 0, stream>>>(y, buckets, bcur, dinv, b, gamma, beta, out);
}

// Round 5
// 561.551 us; speedup vs baseline: 6.7003x; 6.7003x over previous
//
#include <hip/hip_runtime.h>

#define N_NODES 100000
#define N_EDGES 3200000
#define D 128
#define NSLICE 8
#define SLICE_N 12500   // N_NODES / NSLICE

__device__ __forceinline__ float bf2f(unsigned short u) {
  return __uint_as_float(((unsigned)u) << 16);
}
__device__ __forceinline__ unsigned short f2bf(float f) {
  unsigned u = __float_as_uint(f);
  u += 0x7FFF + ((u >> 16) & 1);   // round-to-nearest-even
  return (unsigned short)(u >> 16);
}

// Detect whether edge_index arrived as int64 (odd int32 words all zero) or int32.
__global__ void detect_kernel(const int* __restrict__ ei32, int* __restrict__ flag) {
  __shared__ int anynz;
  if (threadIdx.x == 0) anynz = 0;
  __syncthreads();
  int v = 0;
  for (int i = threadIdx.x; i < 2048; i += 256) v |= ei32[2 * i + 1];
  if (v) atomicOr(&anynz, 1);
  __syncthreads();
  if (threadIdx.x == 0) *flag = (anynz == 0) ? 1 : 0;
}

__global__ void zero_kernel(int* __restrict__ p, int n) {
  int i = blockIdx.x * blockDim.x + threadIdx.x;
  if (i < n) p[i] = 0;
}

// One edge pass: degree count + compact (r,c) into int2 (8B coalesced stores).
__global__ void count_compact_kernel(const void* __restrict__ edges,
                                     const int* __restrict__ flag,
                                     int* __restrict__ cnt, int2* __restrict__ ec) {
  const bool is64 = (*flag != 0);
  int stride = gridDim.x * blockDim.x;
  for (int e = blockIdx.x * blockDim.x + threadIdx.x; e < N_EDGES; e += stride) {
    int r, c;
    if (is64) {
      r = (int)((const long long*)edges)[e];
      c = (int)((const long long*)edges)[N_EDGES + e];
    } else {
      r = ((const int*)edges)[e];
      c = ((const int*)edges)[N_EDGES + e];
    }
    ec[e] = make_int2(r, c);
    atomicAdd(&cnt[r], 1);
  }
}

// Block-level exclusive scan over 1024-element chunks; also emits dinv = rsqrt(deg+1).
__global__ __launch_bounds__(256) void scan1_kernel(const int* __restrict__ cnt,
                                                    int* __restrict__ startArr,
                                                    float* __restrict__ dinv,
                                                    int* __restrict__ partials) {
  __shared__ int s[256];
  int t = threadIdx.x;
  int base = blockIdx.x * 1024 + t * 4;
  int c[4];
#pragma unroll
  for (int i = 0; i < 4; i++) {
    int idx = base + i;
    c[i] = (idx < N_NODES) ? cnt[idx] : 0;
  }
  s[t] = c[0] + c[1] + c[2] + c[3];
  __syncthreads();
#pragma unroll
  for (int off = 1; off < 256; off <<= 1) {
    int v = (t >= off) ? s[t - off] : 0;
    __syncthreads();
    s[t] += v;
    __syncthreads();
  }
  if (t == 255) partials[blockIdx.x] = s[255];
  int run = (t == 0) ? 0 : s[t - 1];
#pragma unroll
  for (int i = 0; i < 4; i++) {
    int idx = base + i;
    if (idx < N_NODES) {
      startArr[idx] = run;
      dinv[idx] = rsqrtf((float)(c[i] + 1));  // +1 self-loop
    }
    run += c[i];
  }
}

__global__ void scan2_kernel(int* __restrict__ partials, int nch) {
  __shared__ int s[128];
  int t = threadIdx.x;
  s[t] = (t < nch) ? partials[t] : 0;
  __syncthreads();
  for (int off = 1; off < 128; off <<= 1) {
    int v = (t >= off) ? s[t - off] : 0;
    __syncthreads();
    s[t] += v;
    __syncthreads();
  }
  partials[t] = (t == 0) ? 0 : s[t - 1];
}

__global__ void scan3_kernel(int* __restrict__ startArr, const int* __restrict__ partials,
                             int* __restrict__ cur) {
  int i = blockIdx.x * blockDim.x + threadIdx.x;
  if (i < N_NODES) {
    int v = startArr[i] + partials[i >> 10];
    startArr[i] = v;
    cur[i] = v;
  }
}

// CSR fill, destination-sliced: slice = blockIdx&7 (XCD-affine under round-robin
// dispatch; perf heuristic only). Each slice's csr window is ~1.6MB -> L2-resident,
// so the scattered 4B stores fill cachelines instead of dirtying 195MB.
__global__ void fill8_kernel(const int2* __restrict__ ec, int* __restrict__ cur,
                             int* __restrict__ csr) {
  int slice = blockIdx.x & (NSLICE - 1);
  int sb = blockIdx.x >> 3;
  int nb = gridDim.x >> 3;
  int lo = slice * SLICE_N, hi = lo + SLICE_N;
  int stride = nb * blockDim.x;
  for (int e = sb * blockDim.x + threadIdx.x; e < N_EDGES; e += stride) {
    int2 rc = ec[e];
    if (rc.x >= lo && rc.x < hi) {
      int pos = atomicAdd(&cur[rc.x], 1);
      csr[pos] = rc.y;
    }
  }
}

// y[n][d] = bf16( dinv[n] * (x @ W)[n][d] )
__global__ __launch_bounds__(256) void gemm_kernel(const float* __restrict__ x,
                                                   const float* __restrict__ W,
                                                   const float* __restrict__ dinv,
                                                   unsigned short* __restrict__ y) {
  __shared__ float xs[32][132];   // [row][k], padded
  __shared__ float ws[32][128];   // [k][col] chunk
  int tid = threadIdx.x;
  int row0 = blockIdx.x * 32;
#pragma unroll
  for (int i = 0; i < 4; i++) {
    int idx = tid + i * 256;
    int m = idx >> 5, c4 = (idx & 31) << 2;
    *(float4*)&xs[m][c4] = *(const float4*)(x + (size_t)(row0 + m) * D + c4);
  }
  float acc[4][4] = {};
  int tx = tid & 31, ty = tid >> 5;  // cols tx*4.., rows ty*4..
  for (int k0 = 0; k0 < 128; k0 += 32) {
#pragma unroll
    for (int i = 0; i < 4; i++) {
      int idx = tid + i * 256;
      int kk = idx >> 5, c4 = (idx & 31) << 2;
      *(float4*)&ws[kk][c4] = *(const float4*)(W + (size_t)(k0 + kk) * D + c4);
    }
    __syncthreads();
#pragma unroll
    for (int k = 0; k < 32; k += 4) {
      float4 a0 = *(float4*)&xs[ty * 4 + 0][k0 + k];
      float4 a1 = *(float4*)&xs[ty * 4 + 1][k0 + k];
      float4 a2 = *(float4*)&xs[ty * 4 + 2][k0 + k];
      float4 a3 = *(float4*)&xs[ty * 4 + 3][k0 + k];
      float4 w0 = *(float4*)&ws[k + 0][tx * 4];
      float4 w1 = *(float4*)&ws[k + 1][tx * 4];
      float4 w2 = *(float4*)&ws[k + 2][tx * 4];
      float4 w3 = *(float4*)&ws[k + 3][tx * 4];
#define ROWFMA(i, ai)                                              \
      acc[i][0] += ai.x * w0.x + ai.y * w1.x + ai.z * w2.x + ai.w * w3.x; \
      acc[i][1] += ai.x * w0.y + ai.y * w1.y + ai.z * w2.y + ai.w * w3.y; \
      acc[i][2] += ai.x * w0.z + ai.y * w1.z + ai.z * w2.z + ai.w * w3.z; \
      acc[i][3] += ai.x * w0.w + ai.y * w1.w + ai.z * w2.w + ai.w * w3.w;
      ROWFMA(0, a0)
      ROWFMA(1, a1)
      ROWFMA(2, a2)
      ROWFMA(3, a3)
#undef ROWFMA
    }
    __syncthreads();
  }
#pragma unroll
  for (int i = 0; i < 4; i++) {
    int row = row0 + ty * 4 + i;
    float di = dinv[row];
    unsigned short h0 = f2bf(di * acc[i][0]);
    unsigned short h1 = f2bf(di * acc[i][1]);
    unsigned short h2 = f2bf(di * acc[i][2]);
    unsigned short h3 = f2bf(di * acc[i][3]);
    uint2 pk;
    pk.x = (unsigned)h0 | ((unsigned)h1 << 16);
    pk.y = (unsigned)h2 | ((unsigned)h3 << 16);
    *(uint2*)(y + (size_t)row * D + tx * 4) = pk;
  }
}

// One wave per node (R1 structure: max wave-parallelism, register accumulation).
// Unrolled to 4 edges in flight for MLP.
__global__ __launch_bounds__(256) void agg_ln_kernel(
    const unsigned short* __restrict__ y, const int* __restrict__ csr,
    const int* __restrict__ startArr, const int* __restrict__ cnt,
    const float* __restrict__ dinv, const float* __restrict__ bias,
    const float* __restrict__ gamma, const float* __restrict__ beta,
    float* __restrict__ out) {
  int wid = threadIdx.x >> 6, lane = threadIdx.x & 63;
  int node = blockIdx.x * 4 + wid;
  if (node >= N_NODES) return;
  const unsigned short* yl = y + 2 * lane;
  int s = startArr[node];
  int n = cnt[node];
  ushort2 sv = *(const ushort2*)(yl + (size_t)node * D);  // self-loop term
  float acc0 = bf2f(sv.x), acc1 = bf2f(sv.y);
  for (int j = 0; j < n; j += 64) {
    int m = n - j;
    if (m > 64) m = 64;
    int cj = (j + lane < n) ? csr[s + j + lane] : 0;
    int t = 0;
    for (; t + 3 < m; t += 4) {   // 4 edges in flight
      int c0 = __shfl(cj, t);
      int c1 = __shfl(cj, t + 1);
      int c2 = __shfl(cj, t + 2);
      int c3 = __shfl(cj, t + 3);
      ushort2 v0 = *(const ushort2*)(yl + (size_t)c0 * D);
      ushort2 v1 = *(const ushort2*)(yl + (size_t)c1 * D);
      ushort2 v2 = *(const ushort2*)(yl + (size_t)c2 * D);
      ushort2 v3 = *(const ushort2*)(yl + (size_t)c3 * D);
      acc0 += bf2f(v0.x) + bf2f(v1.x) + bf2f(v2.x) + bf2f(v3.x);
      acc1 += bf2f(v0.y) + bf2f(v1.y) + bf2f(v2.y) + bf2f(v3.y);
    }
    for (; t < m; t++) {
      int c0 = __shfl(cj, t);
      ushort2 v0 = *(const ushort2*)(yl + (size_t)c0 * D);
      acc0 += bf2f(v0.x);
      acc1 += bf2f(v0.y);
    }
  }
  float di = dinv[node];
  float v0 = fmaf(di, acc0, bias[2 * lane]);
  float v1 = fmaf(di, acc1, bias[2 * lane + 1]);
  float sum = v0 + v1;
#pragma unroll
  for (int msk = 1; msk <= 32; msk <<= 1) sum += __shfl_xor(sum, msk);
  float mu = sum * (1.0f / 128.0f);
  float d0 = v0 - mu, d1 = v1 - mu;
  float sq = d0 * d0 + d1 * d1;
#pragma unroll
  for (int msk = 1; msk <= 32; msk <<= 1) sq += __shfl_xor(sq, msk);
  float rstd = rsqrtf(sq * (1.0f / 128.0f) + 1e-5f);
  float h0 = fmaxf(fmaf(d0 * rstd, gamma[2 * lane], beta[2 * lane]), 0.0f);
  float h1 = fmaxf(fmaf(d1 * rstd, gamma[2 * lane + 1], beta[2 * lane + 1]), 0.0f);
  float2 o;
  o.x = h0;
  o.y = h1;
  *(float2*)(out + (size_t)node * D + 2 * lane) = o;
}

extern "C" void kernel_launch(void* const* d_in, const int* in_sizes, int n_in,
                              void* d_out, int out_size, void* d_ws, size_t ws_size,
                              hipStream_t stream) {
  const float* x = (const float*)d_in[0];
  const void* edges = d_in[1];
  const float* W = (const float*)d_in[2];
  const float* b = (const float*)d_in[3];
  const float* gamma = (const float*)d_in[4];
  const float* beta = (const float*)d_in[5];
  float* out = (float*)d_out;

  char* w = (char*)d_ws;
  size_t off = 0;
  auto take = [&](size_t bytes) {
    size_t r = off;
    off += (bytes + 255) & ~(size_t)255;
    return r;
  };
  int* flag = (int*)(w + take(256));
  int* cnt = (int*)(w + take((size_t)N_NODES * 4));
  int* startArr = (int*)(w + take((size_t)N_NODES * 4));
  int* cur = (int*)(w + take((size_t)N_NODES * 4));
  float* dinv = (float*)(w + take((size_t)N_NODES * 4));
  int* partials = (int*)(w + take(512));
  int* csr = (int*)(w + take((size_t)N_EDGES * 4));
  // ec (int2, 25.6MB) aliases y (bf16, 25.6MB): ec dead after fill8, y born in gemm.
  size_t shared_off = take((size_t)N_EDGES * 8);
  int2* ec = (int2*)(w + shared_off);
  unsigned short* y = (unsigned short*)(w + shared_off);

  detect_kernel<<<1, 256, 0, stream>>>((const int*)edges, flag);
  zero_kernel<<<(N_NODES + 255) / 256, 256, 0, stream>>>(cnt, N_NODES);
  count_compact_kernel<<<2048, 256, 0, stream>>>(edges, flag, cnt, ec);
  scan1_kernel<<<98, 256, 0, stream>>>(cnt, startArr, dinv, partials);
  scan2_kernel<<<1, 128, 0, stream>>>(partials, 98);
  scan3_kernel<<<(N_NODES + 255) / 256, 256, 0, stream>>>(startArr, partials, cur);
  fill8_kernel<<<2048, 256, 0, stream>>>(ec, cur, csr);
  gemm_kernel<<<N_NODES / 32, 256, 0, stream>>>(x, W, dinv, y);
  agg_ln_kernel<<<(N_NODES + 3) / 4, 256, 0, stream>>>(y, csr, startArr, cnt, dinv, b, gamma,
                                                       beta, out);
}

// Round 8
// 352.853 us; speedup vs baseline: 10.6633x; 1.5915x over previous
//
#include <hip/hip_runtime.h>

#define N_NODES 100000
#define N_EDGES 3200000
#define D 128
#define NB 782        // buckets of 128 destination nodes
#define BCAP 5120     // per-bucket entry capacity (mean 4093, sigma~64 -> +16 sigma)
#define STAGE 16      // entries staged per bucket = one 64B cacheline

__device__ __forceinline__ float bf2f(unsigned short u) {
  return __uint_as_float(((unsigned)u) << 16);
}
__device__ __forceinline__ unsigned short f2bf(float f) {
  unsigned u = __float_as_uint(f);
  u += 0x7FFF + ((u >> 16) & 1);   // round-to-nearest-even
  return (unsigned short)(u >> 16);
}

// Detect whether edge_index arrived as int64 (odd int32 words all zero) or int32.
__global__ void detect_kernel(const int* __restrict__ ei32, int* __restrict__ flag) {
  __shared__ int anynz;
  if (threadIdx.x == 0) anynz = 0;
  __syncthreads();
  int v = 0;
  for (int i = threadIdx.x; i < 2048; i += 256) v |= ei32[2 * i + 1];
  if (v) atomicOr(&anynz, 1);
  __syncthreads();
  if (threadIdx.x == 0) *flag = (anynz == 0) ? 1 : 0;
}

__global__ void zero_kernel(int* __restrict__ p, int n) {
  int i = blockIdx.x * blockDim.x + threadIdx.x;
  if (i < n) p[i] = 0;
}

// Pass A: partition edges into 782 dest-buckets. Each block stages 16-entry
// (64B) per-bucket chunks in LDS and flushes FULL CACHELINES via a chunked
// global cursor -> write-allocate traffic ~13MB instead of fill8's 180MB of
// partial-line evictions. Entry = (r&127)<<17 | c (24 bits).
__global__ __launch_bounds__(256) void partition_kernel(const void* __restrict__ edges,
                                                        const int* __restrict__ flag,
                                                        int* __restrict__ gcur,
                                                        unsigned int* __restrict__ bstore) {
  __shared__ unsigned int stage[NB][STAGE];  // 50 KB
  __shared__ int scnt[NB];                   // 3.1 KB
  const bool is64 = (*flag != 0);
  for (int i = threadIdx.x; i < NB; i += 256) scnt[i] = 0;
  __syncthreads();
  int gstride = gridDim.x * blockDim.x;
  for (int base = blockIdx.x * blockDim.x; base < N_EDGES; base += gstride) {
    int e = base + threadIdx.x;
    if (e < N_EDGES) {
      int r, c;
      if (is64) {
        r = (int)((const long long*)edges)[e];
        c = (int)((const long long*)edges)[N_EDGES + e];
      } else {
        r = ((const int*)edges)[e];
        c = ((const int*)edges)[N_EDGES + e];
      }
      int b = r >> 7;
      unsigned ent = ((unsigned)(r & 127) << 17) | (unsigned)c;
      int pos = atomicAdd(&scnt[b], 1);
      if (pos < STAGE) {
        stage[b][pos] = ent;
      } else {  // overflow slow-path (P ~ 1e-10 per iter): per-entry append
        int gp = atomicAdd(&gcur[b], 1);
        if (gp < BCAP) bstore[(size_t)b * BCAP + gp] = ent;
      }
    }
    __syncthreads();
    // flush any bucket whose stage is full: one full 64B line per flush
    for (int b = threadIdx.x; b < NB; b += 256) {
      if (scnt[b] >= STAGE) {
        int gp = atomicAdd(&gcur[b], STAGE);
        if (gp + STAGE <= BCAP) {
          uint4* dst = (uint4*)&bstore[(size_t)b * BCAP + gp];
          uint4* src = (uint4*)&stage[b][0];
          dst[0] = src[0];
          dst[1] = src[1];
          dst[2] = src[2];
          dst[3] = src[3];
        } else {
          for (int k = 0; k < STAGE; k++)
            if (gp + k < BCAP) bstore[(size_t)b * BCAP + gp + k] = stage[b][k];
        }
        scnt[b] = 0;
      }
    }
    __syncthreads();
  }
  // final partial flush
  for (int b = threadIdx.x; b < NB; b += 256) {
    int n = scnt[b];
    if (n > STAGE) n = STAGE;
    if (n > 0) {
      int gp = atomicAdd(&gcur[b], n);
      for (int k = 0; k < n; k++)
        if (gp + k < BCAP) bstore[(size_t)b * BCAP + gp + k] = stage[b][k];
    }
  }
}

// Pass B: one block per bucket. Load entries to LDS, count local degrees,
// exclusive scan, emit start/cnt/dinv, scatter back IN-PLACE (sorted by node,
// value = src col). Window is L2-hot (just read) -> writebacks ~13MB once.
__global__ __launch_bounds__(256) void bucket_kernel(const int* __restrict__ gcur,
                                                     unsigned int* __restrict__ bstore,
                                                     int* __restrict__ cnt,
                                                     int* __restrict__ start,
                                                     float* __restrict__ dinv) {
  __shared__ unsigned int ent[BCAP];  // 20 KB
  __shared__ int lcnt[128];
  __shared__ int s[128];
  __shared__ int loffs[128];
  int b = blockIdx.x, tid = threadIdx.x;
  size_t base = (size_t)b * BCAP;
  int m = gcur[b];
  if (m > BCAP) m = BCAP;
  int nodes = N_NODES - b * 128;
  if (nodes > 128) nodes = 128;

  for (int i = tid; i < m; i += 256) ent[i] = bstore[base + i];
  if (tid < 128) lcnt[tid] = 0;
  __syncthreads();
  for (int i = tid; i < m; i += 256) atomicAdd(&lcnt[ent[i] >> 17], 1);
  __syncthreads();
  if (tid < 128) s[tid] = lcnt[tid];
  __syncthreads();
#pragma unroll
  for (int off = 1; off < 128; off <<= 1) {
    int v = (tid < 128 && tid >= off) ? s[tid - off] : 0;
    __syncthreads();
    if (tid < 128) s[tid] += v;
    __syncthreads();
  }
  if (tid < nodes) {
    int st = (tid == 0) ? 0 : s[tid - 1];
    int node = b * 128 + tid;
    start[node] = (int)base + st;
    cnt[node] = lcnt[tid];
    dinv[node] = rsqrtf((float)(lcnt[tid] + 1));  // +1 self-loop
    loffs[tid] = st;
  }
  __syncthreads();
  for (int i = tid; i < m; i += 256) {
    unsigned u = ent[i];
    int lr = u >> 17;
    int pos = atomicAdd(&loffs[lr], 1);
    bstore[base + pos] = u & 0x1FFFF;  // store src col only
  }
}

// y[n][d] = bf16( dinv[n] * (x @ W)[n][d] )
__global__ __launch_bounds__(256) void gemm_kernel(const float* __restrict__ x,
                                                   const float* __restrict__ W,
                                                   const float* __restrict__ dinv,
                                                   unsigned short* __restrict__ y) {
  __shared__ float xs[32][132];   // [row][k], padded
  __shared__ float ws[32][128];   // [k][col] chunk
  int tid = threadIdx.x;
  int row0 = blockIdx.x * 32;
#pragma unroll
  for (int i = 0; i < 4; i++) {
    int idx = tid + i * 256;
    int m = idx >> 5, c4 = (idx & 31) << 2;
    *(float4*)&xs[m][c4] = *(const float4*)(x + (size_t)(row0 + m) * D + c4);
  }
  float acc[4][4] = {};
  int tx = tid & 31, ty = tid >> 5;  // cols tx*4.., rows ty*4..
  for (int k0 = 0; k0 < 128; k0 += 32) {
#pragma unroll
    for (int i = 0; i < 4; i++) {
      int idx = tid + i * 256;
      int kk = idx >> 5, c4 = (idx & 31) << 2;
      *(float4*)&ws[kk][c4] = *(const float4*)(W + (size_t)(k0 + kk) * D + c4);
    }
    __syncthreads();
#pragma unroll
    for (int k = 0; k < 32; k += 4) {
      float4 a0 = *(float4*)&xs[ty * 4 + 0][k0 + k];
      float4 a1 = *(float4*)&xs[ty * 4 + 1][k0 + k];
      float4 a2 = *(float4*)&xs[ty * 4 + 2][k0 + k];
      float4 a3 = *(float4*)&xs[ty * 4 + 3][k0 + k];
      float4 w0 = *(float4*)&ws[k + 0][tx * 4];
      float4 w1 = *(float4*)&ws[k + 1][tx * 4];
      float4 w2 = *(float4*)&ws[k + 2][tx * 4];
      float4 w3 = *(float4*)&ws[k + 3][tx * 4];
#define ROWFMA(i, ai)                                              \
      acc[i][0] += ai.x * w0.x + ai.y * w1.x + ai.z * w2.x + ai.w * w3.x; \
      acc[i][1] += ai.x * w0.y + ai.y * w1.y + ai.z * w2.y + ai.w * w3.y; \
      acc[i][2] += ai.x * w0.z + ai.y * w1.z + ai.z * w2.z + ai.w * w3.z; \
      acc[i][3] += ai.x * w0.w + ai.y * w1.w + ai.z * w2.w + ai.w * w3.w;
      ROWFMA(0, a0)
      ROWFMA(1, a1)
      ROWFMA(2, a2)
      ROWFMA(3, a3)
#undef ROWFMA
    }
    __syncthreads();
  }
#pragma unroll
  for (int i = 0; i < 4; i++) {
    int row = row0 + ty * 4 + i;
    float di = dinv[row];
    unsigned short h0 = f2bf(di * acc[i][0]);
    unsigned short h1 = f2bf(di * acc[i][1]);
    unsigned short h2 = f2bf(di * acc[i][2]);
    unsigned short h3 = f2bf(di * acc[i][3]);
    uint2 pk;
    pk.x = (unsigned)h0 | ((unsigned)h1 << 16);
    pk.y = (unsigned)h2 | ((unsigned)h3 << 16);
    *(uint2*)(y + (size_t)row * D + tx * 4) = pk;
  }
}

// One wave per node (max wave-parallelism, register accumulation), 4 edges in flight.
__global__ __launch_bounds__(256) void agg_ln_kernel(
    const unsigned short* __restrict__ y, const unsigned int* __restrict__ csr,
    const int* __restrict__ start, const int* __restrict__ cnt,
    const float* __restrict__ dinv, const float* __restrict__ bias,
    const float* __restrict__ gamma, const float* __restrict__ beta,
    float* __restrict__ out) {
  int wid = threadIdx.x >> 6, lane = threadIdx.x & 63;
  int node = blockIdx.x * 4 + wid;
  if (node >= N_NODES) return;
  const unsigned short* yl = y + 2 * lane;
  int s = start[node];
  int n = cnt[node];
  ushort2 sv = *(const ushort2*)(yl + (size_t)node * D);  // self-loop term
  float acc0 = bf2f(sv.x), acc1 = bf2f(sv.y);
  for (int j = 0; j < n; j += 64) {
    int m = n - j;
    if (m > 64) m = 64;
    int cj = (j + lane < n) ? (int)csr[s + j + lane] : 0;
    int t = 0;
    for (; t + 3 < m; t += 4) {   // 4 edges in flight
      int c0 = __shfl(cj, t);
      int c1 = __shfl(cj, t + 1);
      int c2 = __shfl(cj, t + 2);
      int c3 = __shfl(cj, t + 3);
      ushort2 v0 = *(const ushort2*)(yl + (size_t)c0 * D);
      ushort2 v1 = *(const ushort2*)(yl + (size_t)c1 * D);
      ushort2 v2 = *(const ushort2*)(yl + (size_t)c2 * D);
      ushort2 v3 = *(const ushort2*)(yl + (size_t)c3 * D);
      acc0 += bf2f(v0.x) + bf2f(v1.x) + bf2f(v2.x) + bf2f(v3.x);
      acc1 += bf2f(v0.y) + bf2f(v1.y) + bf2f(v2.y) + bf2f(v3.y);
    }
    for (; t < m; t++) {
      int c0 = __shfl(cj, t);
      ushort2 v0 = *(const ushort2*)(yl + (size_t)c0 * D);
      acc0 += bf2f(v0.x);
      acc1 += bf2f(v0.y);
    }
  }
  float di = dinv[node];
  float v0 = fmaf(di, acc0, bias[2 * lane]);
  float v1 = fmaf(di, acc1, bias[2 * lane + 1]);
  float sum = v0 + v1;
#pragma unroll
  for (int msk = 1; msk <= 32; msk <<= 1) sum += __shfl_xor(sum, msk);
  float mu = sum * (1.0f / 128.0f);
  float d0 = v0 - mu, d1 = v1 - mu;
  float sq = d0 * d0 + d1 * d1;
#pragma unroll
  for (int msk = 1; msk <= 32; msk <<= 1) sq += __shfl_xor(sq, msk);
  float rstd = rsqrtf(sq * (1.0f / 128.0f) + 1e-5f);
  float h0 = fmaxf(fmaf(d0 * rstd, gamma[2 * lane], beta[2 * lane]), 0.0f);
  float h1 = fmaxf(fmaf(d1 * rstd, gamma[2 * lane + 1], beta[2 * lane + 1]), 0.0f);
  float2 o;
  o.x = h0;
  o.y = h1;
  *(float2*)(out + (size_t)node * D + 2 * lane) = o;
}

extern "C" void kernel_launch(void* const* d_in, const int* in_sizes, int n_in,
                              void* d_out, int out_size, void* d_ws, size_t ws_size,
                              hipStream_t stream) {
  const float* x = (const float*)d_in[0];
  const void* edges = d_in[1];
  const float* W = (const float*)d_in[2];
  const float* b = (const float*)d_in[3];
  const float* gamma = (const float*)d_in[4];
  const float* beta = (const float*)d_in[5];
  float* out = (float*)d_out;

  char* w = (char*)d_ws;
  size_t off = 0;
  auto take = [&](size_t bytes) {
    size_t r = off;
    off += (bytes + 255) & ~(size_t)255;
    return r;
  };
  int* flag = (int*)(w + take(256));
  int* gcur = (int*)(w + take((size_t)NB * 4));
  int* cnt = (int*)(w + take((size_t)N_NODES * 4));
  int* start = (int*)(w + take((size_t)N_NODES * 4));
  float* dinv = (float*)(w + take((size_t)N_NODES * 4));
  unsigned int* bstore = (unsigned int*)(w + take((size_t)NB * BCAP * 4));  // 16 MB
  unsigned short* y = (unsigned short*)(w + take((size_t)N_NODES * D * 2)); // 25.6 MB

  detect_kernel<<<1, 256, 0, stream>>>((const int*)edges, flag);
  zero_kernel<<<(NB + 255) / 256, 256, 0, stream>>>(gcur, NB);
  partition_kernel<<<768, 256, 0, stream>>>(edges, flag, gcur, bstore);
  bucket_kernel<<<NB, 256, 0, stream>>>(gcur, bstore, cnt, start, dinv);
  gemm_kernel<<<N_NODES / 32, 256, 0, stream>>>(x, W, dinv, y);
  agg_ln_kernel<<<(N_NODES + 3) / 4, 256, 0, stream>>>(y, bstore, start, cnt, dinv, b, gamma,
                                                       beta, out);
}

// Round 9
// 328.799 us; speedup vs baseline: 11.4434x; 1.0732x over previous
//
#include <hip/hip_runtime.h>

#define N_NODES 100000
#define N_EDGES 3200000
#define D 128
#define NB 782        // buckets of 128 destination nodes
#define BCAP 5120     // per-bucket entry capacity (mean 4093, sigma~64 -> +16 sigma)
#define STAGE 16      // entries staged per bucket = one 64B cacheline

typedef __attribute__((ext_vector_type(8))) short bf16x8;
typedef __attribute__((ext_vector_type(4))) float f32x4;

__device__ __forceinline__ float bf2f(unsigned short u) {
  return __uint_as_float(((unsigned)u) << 16);
}
__device__ __forceinline__ unsigned short f2bf(float f) {
  unsigned u = __float_as_uint(f);
  u += 0x7FFF + ((u >> 16) & 1);   // round-to-nearest-even
  return (unsigned short)(u >> 16);
}

// Detect whether edge_index arrived as int64 (odd int32 words all zero) or int32.
__global__ void detect_kernel(const int* __restrict__ ei32, int* __restrict__ flag) {
  __shared__ int anynz;
  if (threadIdx.x == 0) anynz = 0;
  __syncthreads();
  int v = 0;
  for (int i = threadIdx.x; i < 2048; i += 256) v |= ei32[2 * i + 1];
  if (v) atomicOr(&anynz, 1);
  __syncthreads();
  if (threadIdx.x == 0) *flag = (anynz == 0) ? 1 : 0;
}

__global__ void zero_kernel(int* __restrict__ p, int n) {
  int i = blockIdx.x * blockDim.x + threadIdx.x;
  if (i < n) p[i] = 0;
}

// W[k][c] f32 -> wTg[c][k] bf16 (one-off, 64KB read)
__global__ void prep_w_kernel(const float* __restrict__ W, unsigned short* __restrict__ wTg) {
  int t = threadIdx.x;
  int c = t >> 1, h = t & 1;
  for (int k0 = h * 64; k0 < h * 64 + 64; k0 += 8) {
    unsigned short tmp[8];
#pragma unroll
    for (int j = 0; j < 8; j++) tmp[j] = f2bf(W[(k0 + j) * D + c]);
    *(uint4*)(wTg + c * D + k0) = *(uint4*)tmp;
  }
}

// Pass A: partition edges into 782 dest-buckets; LDS-staged 64B-line flushes.
__global__ __launch_bounds__(256) void partition_kernel(const void* __restrict__ edges,
                                                        const int* __restrict__ flag,
                                                        int* __restrict__ gcur,
                                                        unsigned int* __restrict__ bstore) {
  __shared__ unsigned int stage[NB][STAGE];  // 50 KB
  __shared__ int scnt[NB];                   // 3.1 KB
  const bool is64 = (*flag != 0);
  for (int i = threadIdx.x; i < NB; i += 256) scnt[i] = 0;
  __syncthreads();
  int gstride = gridDim.x * blockDim.x;
  for (int base = blockIdx.x * blockDim.x; base < N_EDGES; base += gstride) {
    int e = base + threadIdx.x;
    if (e < N_EDGES) {
      int r, c;
      if (is64) {
        r = (int)((const long long*)edges)[e];
        c = (int)((const long long*)edges)[N_EDGES + e];
      } else {
        r = ((const int*)edges)[e];
        c = ((const int*)edges)[N_EDGES + e];
      }
      int b = r >> 7;
      unsigned ent = ((unsigned)(r & 127) << 17) | (unsigned)c;
      int pos = atomicAdd(&scnt[b], 1);
      if (pos < STAGE) {
        stage[b][pos] = ent;
      } else {  // overflow slow-path: per-entry append
        int gp = atomicAdd(&gcur[b], 1);
        if (gp < BCAP) bstore[(size_t)b * BCAP + gp] = ent;
      }
    }
    __syncthreads();
    for (int b = threadIdx.x; b < NB; b += 256) {
      if (scnt[b] >= STAGE) {
        int gp = atomicAdd(&gcur[b], STAGE);
        if (gp + STAGE <= BCAP) {
          uint4* dst = (uint4*)&bstore[(size_t)b * BCAP + gp];
          uint4* src = (uint4*)&stage[b][0];
          dst[0] = src[0];
          dst[1] = src[1];
          dst[2] = src[2];
          dst[3] = src[3];
        } else {
          for (int k = 0; k < STAGE; k++)
            if (gp + k < BCAP) bstore[(size_t)b * BCAP + gp + k] = stage[b][k];
        }
        scnt[b] = 0;
      }
    }
    __syncthreads();
  }
  for (int b = threadIdx.x; b < NB; b += 256) {
    int n = scnt[b];
    if (n > STAGE) n = STAGE;
    if (n > 0) {
      int gp = atomicAdd(&gcur[b], n);
      for (int k = 0; k < n; k++)
        if (gp + k < BCAP) bstore[(size_t)b * BCAP + gp + k] = stage[b][k];
    }
  }
}

// Pass B: per-bucket LDS sort -> start/cnt/dinv + in-place src-col scatter.
__global__ __launch_bounds__(256) void bucket_kernel(const int* __restrict__ gcur,
                                                     unsigned int* __restrict__ bstore,
                                                     int* __restrict__ cnt,
                                                     int* __restrict__ start,
                                                     float* __restrict__ dinv) {
  __shared__ unsigned int ent[BCAP];  // 20 KB
  __shared__ int lcnt[128];
  __shared__ int s[128];
  __shared__ int loffs[128];
  int b = blockIdx.x, tid = threadIdx.x;
  size_t base = (size_t)b * BCAP;
  int m = gcur[b];
  if (m > BCAP) m = BCAP;
  int nodes = N_NODES - b * 128;
  if (nodes > 128) nodes = 128;

  for (int i = tid; i < m; i += 256) ent[i] = bstore[base + i];
  if (tid < 128) lcnt[tid] = 0;
  __syncthreads();
  for (int i = tid; i < m; i += 256) atomicAdd(&lcnt[ent[i] >> 17], 1);
  __syncthreads();
  if (tid < 128) s[tid] = lcnt[tid];
  __syncthreads();
#pragma unroll
  for (int off = 1; off < 128; off <<= 1) {
    int v = (tid < 128 && tid >= off) ? s[tid - off] : 0;
    __syncthreads();
    if (tid < 128) s[tid] += v;
    __syncthreads();
  }
  if (tid < nodes) {
    int st = (tid == 0) ? 0 : s[tid - 1];
    int node = b * 128 + tid;
    start[node] = (int)base + st;
    cnt[node] = lcnt[tid];
    dinv[node] = rsqrtf((float)(lcnt[tid] + 1));  // +1 self-loop
    loffs[tid] = st;
  }
  __syncthreads();
  for (int i = tid; i < m; i += 256) {
    unsigned u = ent[i];
    int lr = u >> 17;
    int pos = atomicAdd(&loffs[lr], 1);
    bstore[base + pos] = u & 0x1FFFF;  // store src col only
  }
}

// MFMA gemm: y[n][d] = bf16(dinv[n] * (x@W)[n][d]). 64 rows/block, 4 waves.
// LDS rows padded to 272B (uniform bank phase for b128 fragment reads).
// A and B fragments both packed with the SAME contiguous-k convention
// (k = kt*32 + 8*(lane>>4) + i) -> any HW k-slot permutation cancels.
// C/D: col=lane&15, row=4*(lane>>4)+reg (HW-verified mapping).
__global__ __launch_bounds__(256) void gemm_mfma_kernel(const float* __restrict__ x,
                                                        const unsigned short* __restrict__ wTg,
                                                        const float* __restrict__ dinv,
                                                        unsigned short* __restrict__ y) {
  __shared__ unsigned short xs[64 * 136];   // 17.4 KB
  __shared__ unsigned short wls[128 * 136]; // 34.8 KB
  int tid = threadIdx.x;
  int row0 = blockIdx.x * 64;
  {  // stage W^T (bf16, coalesced)
    int c = tid >> 1, h = tid & 1;
    const uint4* src = (const uint4*)(wTg + c * D + h * 64);
    uint4* dst = (uint4*)(wls + c * 136 + h * 64);
#pragma unroll
    for (int i = 0; i < 8; i++) dst[i] = src[i];
  }
  {  // stage x rows -> bf16
    int rx = tid >> 2, q = tid & 3;
    int r = row0 + rx;
    if (r > N_NODES - 1) r = N_NODES - 1;
    const float4* src = (const float4*)(x + (size_t)r * D + q * 32);
    uint4* dst = (uint4*)(xs + rx * 136 + q * 32);
#pragma unroll
    for (int i = 0; i < 4; i++) {
      float4 fa = src[2 * i], fb = src[2 * i + 1];
      uint4 p;
      p.x = (unsigned)f2bf(fa.x) | ((unsigned)f2bf(fa.y) << 16);
      p.y = (unsigned)f2bf(fa.z) | ((unsigned)f2bf(fa.w) << 16);
      p.z = (unsigned)f2bf(fb.x) | ((unsigned)f2bf(fb.y) << 16);
      p.w = (unsigned)f2bf(fb.z) | ((unsigned)f2bf(fb.w) << 16);
      dst[i] = p;
    }
  }
  __syncthreads();
  int w = tid >> 6, l = tid & 63;
  int g = l >> 4, ln = l & 15;
  bf16x8 af[4];
#pragma unroll
  for (int kt = 0; kt < 4; kt++)
    af[kt] = *(const bf16x8*)(xs + (w * 16 + ln) * 136 + kt * 32 + g * 8);
  int rbase = row0 + w * 16 + 4 * g;
  float dv[4];
#pragma unroll
  for (int j = 0; j < 4; j++) {
    int r = rbase + j;
    dv[j] = dinv[r < N_NODES ? r : N_NODES - 1];
  }
#pragma unroll
  for (int ct = 0; ct < 8; ct++) {
    f32x4 acc = {0.f, 0.f, 0.f, 0.f};
#pragma unroll
    for (int kt = 0; kt < 4; kt++) {
      bf16x8 bf = *(const bf16x8*)(wls + (ct * 16 + ln) * 136 + kt * 32 + g * 8);
      acc = __builtin_amdgcn_mfma_f32_16x16x32_bf16(af[kt], bf, acc, 0, 0, 0);
    }
#pragma unroll
    for (int j = 0; j < 4; j++) {
      int r = rbase + j;
      if (r < N_NODES) y[(size_t)r * D + ct * 16 + ln] = f2bf(dv[j] * acc[j]);
    }
  }
}

// One wave per node; TWO edges per load instruction (half-waves), ushort4/lane.
// Fold halves with shfl_xor(32); dims duplicated across halves -> reduce /256.
__global__ __launch_bounds__(256) void agg_ln_kernel(
    const unsigned short* __restrict__ y, const unsigned int* __restrict__ csr,
    const int* __restrict__ start, const int* __restrict__ cnt,
    const float* __restrict__ dinv, const float* __restrict__ bias,
    const float* __restrict__ gamma, const float* __restrict__ beta,
    float* __restrict__ out) {
  int wid = threadIdx.x >> 6, lane = threadIdx.x & 63;
  int node = blockIdx.x * 4 + wid;
  if (node >= N_NODES) return;
  int half = lane >> 5, hl = lane & 31;
  int s = start[node];
  int n = cnt[node];
  float a0 = 0.f, a1 = 0.f, a2 = 0.f, a3 = 0.f;
  for (int j = 0; j < n; j += 64) {
    int m = n - j;
    if (m > 64) m = 64;
    int cj = (j + lane < n) ? (int)csr[s + j + lane] : 0;
    int t = 0;
    for (; t + 7 < m; t += 8) {  // 4 pair-loads (8 edges) in flight
      int e0 = __shfl(cj, t + half);
      int e1 = __shfl(cj, t + 2 + half);
      int e2 = __shfl(cj, t + 4 + half);
      int e3 = __shfl(cj, t + 6 + half);
      ushort4 v0 = *(const ushort4*)(y + (size_t)e0 * D + hl * 4);
      ushort4 v1 = *(const ushort4*)(y + (size_t)e1 * D + hl * 4);
      ushort4 v2 = *(const ushort4*)(y + (size_t)e2 * D + hl * 4);
      ushort4 v3 = *(const ushort4*)(y + (size_t)e3 * D + hl * 4);
      a0 += bf2f(v0.x) + bf2f(v1.x) + bf2f(v2.x) + bf2f(v3.x);
      a1 += bf2f(v0.y) + bf2f(v1.y) + bf2f(v2.y) + bf2f(v3.y);
      a2 += bf2f(v0.z) + bf2f(v1.z) + bf2f(v2.z) + bf2f(v3.z);
      a3 += bf2f(v0.w) + bf2f(v1.w) + bf2f(v2.w) + bf2f(v3.w);
    }
    for (; t + 1 < m; t += 2) {
      int e0 = __shfl(cj, t + half);
      ushort4 v0 = *(const ushort4*)(y + (size_t)e0 * D + hl * 4);
      a0 += bf2f(v0.x);
      a1 += bf2f(v0.y);
      a2 += bf2f(v0.z);
      a3 += bf2f(v0.w);
    }
    if (t < m) {  // odd tail: half 0 only (avoid double count)
      int e0 = __shfl(cj, t);
      if (half == 0) {
        ushort4 v0 = *(const ushort4*)(y + (size_t)e0 * D + hl * 4);
        a0 += bf2f(v0.x);
        a1 += bf2f(v0.y);
        a2 += bf2f(v0.z);
        a3 += bf2f(v0.w);
      }
    }
  }
  // fold half-waves: every lane now holds full edge-sum for its 4 dims
  a0 += __shfl_xor(a0, 32);
  a1 += __shfl_xor(a1, 32);
  a2 += __shfl_xor(a2, 32);
  a3 += __shfl_xor(a3, 32);
  // self-loop (after fold; per-lane copy consistent across halves)
  ushort4 sv = *(const ushort4*)(y + (size_t)node * D + hl * 4);
  a0 += bf2f(sv.x);
  a1 += bf2f(sv.y);
  a2 += bf2f(sv.z);
  a3 += bf2f(sv.w);
  float di = dinv[node];
  float4 bi = *(const float4*)(bias + hl * 4);
  float v0 = fmaf(di, a0, bi.x);
  float v1 = fmaf(di, a1, bi.y);
  float v2 = fmaf(di, a2, bi.z);
  float v3 = fmaf(di, a3, bi.w);
  float sum = v0 + v1 + v2 + v3;
#pragma unroll
  for (int msk = 1; msk <= 32; msk <<= 1) sum += __shfl_xor(sum, msk);
  float mu = sum * (1.0f / 256.0f);  // dims duplicated across halves
  float d0 = v0 - mu, d1 = v1 - mu, d2 = v2 - mu, d3 = v3 - mu;
  float sq = d0 * d0 + d1 * d1 + d2 * d2 + d3 * d3;
#pragma unroll
  for (int msk = 1; msk <= 32; msk <<= 1) sq += __shfl_xor(sq, msk);
  float rstd = rsqrtf(sq * (1.0f / 256.0f) + 1e-5f);
  float4 ga = *(const float4*)(gamma + hl * 4);
  float4 be = *(const float4*)(beta + hl * 4);
  if (half == 0) {
    float4 o;
    o.x = fmaxf(fmaf(d0 * rstd, ga.x, be.x), 0.0f);
    o.y = fmaxf(fmaf(d1 * rstd, ga.y, be.y), 0.0f);
    o.z = fmaxf(fmaf(d2 * rstd, ga.z, be.z), 0.0f);
    o.w = fmaxf(fmaf(d3 * rstd, ga.w, be.w), 0.0f);
    *(float4*)(out + (size_t)node * D + hl * 4) = o;
  }
}

extern "C" void kernel_launch(void* const* d_in, const int* in_sizes, int n_in,
                              void* d_out, int out_size, void* d_ws, size_t ws_size,
                              hipStream_t stream) {
  const float* x = (const float*)d_in[0];
  const void* edges = d_in[1];
  const float* W = (const float*)d_in[2];
  const float* b = (const float*)d_in[3];
  const float* gamma = (const float*)d_in[4];
  const float* beta = (const float*)d_in[5];
  float* out = (float*)d_out;

  char* w = (char*)d_ws;
  size_t off = 0;
  auto take = [&](size_t bytes) {
    size_t r = off;
    off += (bytes + 255) & ~(size_t)255;
    return r;
  };
  int* flag = (int*)(w + take(256));
  int* gcur = (int*)(w + take((size_t)NB * 4));
  int* cnt = (int*)(w + take((size_t)N_NODES * 4));
  int* start = (int*)(w + take((size_t)N_NODES * 4));
  float* dinv = (float*)(w + take((size_t)N_NODES * 4));
  unsigned short* wTg = (unsigned short*)(w + take((size_t)D * D * 2));     // 32 KB
  unsigned int* bstore = (unsigned int*)(w + take((size_t)NB * BCAP * 4));  // 16 MB
  unsigned short* y = (unsigned short*)(w + take((size_t)N_NODES * D * 2)); // 25.6 MB

  detect_kernel<<<1, 256, 0, stream>>>((const int*)edges, flag);
  zero_kernel<<<(NB + 255) / 256, 256, 0, stream>>>(gcur, NB);
  prep_w_kernel<<<1, 256, 0, stream>>>(W, wTg);
  partition_kernel<<<768, 256, 0, stream>>>(edges, flag, gcur, bstore);
  bucket_kernel<<<NB, 256, 0, stream>>>(gcur, bstore, cnt, start, dinv);
  gemm_mfma_kernel<<<(N_NODES + 63) / 64, 256, 0, stream>>>(x, wTg, dinv, y);
  agg_ln_kernel<<<(N_NODES + 3) / 4, 256, 0, stream>>>(y, bstore, start, cnt, dinv, b, gamma,
                                                       beta, out);
}

// Round 10
// 328.697 us; speedup vs baseline: 11.4470x; 1.0003x over previous
//
#include <hip/hip_runtime.h>

#define N_NODES 100000
#define N_EDGES 3200000
#define D 128
#define NB 782        // buckets of 128 destination nodes
#define BCAP 5120     // per-bucket entry capacity (mean 4093, sigma~64 -> +16 sigma)
#define STAGE 16      // entries staged per bucket = one 64B cacheline
#define NKEY 1024     // 128 local nodes x 8 coarse src ranges

typedef __attribute__((ext_vector_type(8))) short bf16x8;
typedef __attribute__((ext_vector_type(4))) float f32x4;

__device__ __forceinline__ float bf2f(unsigned short u) {
  return __uint_as_float(((unsigned)u) << 16);
}
__device__ __forceinline__ unsigned short f2bf(float f) {
  unsigned u = __float_as_uint(f);
  u += 0x7FFF + ((u >> 16) & 1);   // round-to-nearest-even
  return (unsigned short)(u >> 16);
}

// Detect whether edge_index arrived as int64 (odd int32 words all zero) or int32.
__global__ void detect_kernel(const int* __restrict__ ei32, int* __restrict__ flag) {
  __shared__ int anynz;
  if (threadIdx.x == 0) anynz = 0;
  __syncthreads();
  int v = 0;
  for (int i = threadIdx.x; i < 2048; i += 256) v |= ei32[2 * i + 1];
  if (v) atomicOr(&anynz, 1);
  __syncthreads();
  if (threadIdx.x == 0) *flag = (anynz == 0) ? 1 : 0;
}

// W[k][c] f32 -> wTg[c][k] bf16 (one-off, 64KB read)
__global__ void prep_w_kernel(const float* __restrict__ W, unsigned short* __restrict__ wTg) {
  int t = threadIdx.x;
  int c = t >> 1, h = t & 1;
  for (int k0 = h * 64; k0 < h * 64 + 64; k0 += 8) {
    unsigned short tmp[8];
#pragma unroll
    for (int j = 0; j < 8; j++) tmp[j] = f2bf(W[(k0 + j) * D + c]);
    *(uint4*)(wTg + c * D + k0) = *(uint4*)tmp;
  }
}

// Pass A: partition edges into 782 dest-buckets; LDS-staged 64B-line flushes.
__global__ __launch_bounds__(256) void partition_kernel(const void* __restrict__ edges,
                                                        const int* __restrict__ flag,
                                                        int* __restrict__ gcur,
                                                        unsigned int* __restrict__ bstore) {
  __shared__ unsigned int stage[NB][STAGE];  // 50 KB
  __shared__ int scnt[NB];                   // 3.1 KB
  const bool is64 = (*flag != 0);
  for (int i = threadIdx.x; i < NB; i += 256) scnt[i] = 0;
  __syncthreads();
  int gstride = gridDim.x * blockDim.x;
  for (int base = blockIdx.x * blockDim.x; base < N_EDGES; base += gstride) {
    int e = base + threadIdx.x;
    if (e < N_EDGES) {
      int r, c;
      if (is64) {
        r = (int)((const long long*)edges)[e];
        c = (int)((const long long*)edges)[N_EDGES + e];
      } else {
        r = ((const int*)edges)[e];
        c = ((const int*)edges)[N_EDGES + e];
      }
      int b = r >> 7;
      unsigned ent = ((unsigned)(r & 127) << 17) | (unsigned)c;
      int pos = atomicAdd(&scnt[b], 1);
      if (pos < STAGE) {
        stage[b][pos] = ent;
      } else {  // overflow slow-path: per-entry append
        int gp = atomicAdd(&gcur[b], 1);
        if (gp < BCAP) bstore[(size_t)b * BCAP + gp] = ent;
      }
    }
    __syncthreads();
    for (int b = threadIdx.x; b < NB; b += 256) {
      if (scnt[b] >= STAGE) {
        int gp = atomicAdd(&gcur[b], STAGE);
        if (gp + STAGE <= BCAP) {
          uint4* dst = (uint4*)&bstore[(size_t)b * BCAP + gp];
          uint4* src = (uint4*)&stage[b][0];
          dst[0] = src[0];
          dst[1] = src[1];
          dst[2] = src[2];
          dst[3] = src[3];
        } else {
          for (int k = 0; k < STAGE; k++)
            if (gp + k < BCAP) bstore[(size_t)b * BCAP + gp + k] = stage[b][k];
        }
        scnt[b] = 0;
      }
    }
    __syncthreads();
  }
  for (int b = threadIdx.x; b < NB; b += 256) {
    int n = scnt[b];
    if (n > STAGE) n = STAGE;
    if (n > 0) {
      int gp = atomicAdd(&gcur[b], n);
      for (int k = 0; k < n; k++)
        if (gp + k < BCAP) bstore[(size_t)b * BCAP + gp + k] = stage[b][k];
    }
  }
}

// Pass B: per-bucket counting sort with key = (local_node<<3) | (src>>14).
// Within each node's edge list, edges come out grouped by 8 coarse source
// ranges (~3.2MB of y each) -> concurrently-active agg waves walk ranges in
// near-lockstep, shrinking the instantaneous gather footprint (L2 hit up).
__global__ __launch_bounds__(256) void bucket_kernel(const int* __restrict__ gcur,
                                                     unsigned int* __restrict__ bstore,
                                                     int* __restrict__ cnt,
                                                     int* __restrict__ start,
                                                     float* __restrict__ dinv) {
  __shared__ unsigned int ent[BCAP];  // 20 KB
  __shared__ int kc[NKEY];            // exclusive scan of key counts
  __shared__ int koff[NKEY];          // scatter cursors
  __shared__ int psum[256];
  int b = blockIdx.x, tid = threadIdx.x;
  size_t base = (size_t)b * BCAP;
  int m = gcur[b];
  if (m > BCAP) m = BCAP;
  int nodes = N_NODES - b * 128;
  if (nodes > 128) nodes = 128;

  for (int i = tid; i < m; i += 256) ent[i] = bstore[base + i];
  for (int i = tid; i < NKEY; i += 256) kc[i] = 0;
  __syncthreads();
  for (int i = tid; i < m; i += 256) {
    unsigned u = ent[i];
    int key = (int)(((u >> 17) << 3) | ((u & 0x1FFFFu) >> 14));
    atomicAdd(&kc[key], 1);
  }
  __syncthreads();
  // exclusive scan over 1024 keys: 4/thread serial + 256-wide block scan
  int c0 = kc[4 * tid], c1 = kc[4 * tid + 1], c2 = kc[4 * tid + 2], c3 = kc[4 * tid + 3];
  psum[tid] = c0 + c1 + c2 + c3;
  __syncthreads();
#pragma unroll
  for (int off = 1; off < 256; off <<= 1) {
    int v = (tid >= off) ? psum[tid - off] : 0;
    __syncthreads();
    psum[tid] += v;
    __syncthreads();
  }
  int o = (tid == 0) ? 0 : psum[tid - 1];
  kc[4 * tid] = o;
  kc[4 * tid + 1] = o + c0;
  kc[4 * tid + 2] = o + c0 + c1;
  kc[4 * tid + 3] = o + c0 + c1 + c2;
  koff[4 * tid] = o;
  koff[4 * tid + 1] = o + c0;
  koff[4 * tid + 2] = o + c0 + c1;
  koff[4 * tid + 3] = o + c0 + c1 + c2;
  __syncthreads();
  if (tid < nodes) {
    int st = kc[8 * tid];
    int en = (tid == 127) ? m : kc[8 * (tid + 1)];
    int node = b * 128 + tid;
    start[node] = (int)base + st;
    cnt[node] = en - st;
    dinv[node] = rsqrtf((float)(en - st + 1));  // +1 self-loop
  }
  __syncthreads();
  for (int i = tid; i < m; i += 256) {
    unsigned u = ent[i];
    int key = (int)(((u >> 17) << 3) | ((u & 0x1FFFFu) >> 14));
    int pos = atomicAdd(&koff[key], 1);
    bstore[base + pos] = u & 0x1FFFF;  // store src col only, src-range-ordered
  }
}

// MFMA gemm: y[n][d] = bf16(dinv[n] * (x@W)[n][d]). 64 rows/block, 4 waves.
__global__ __launch_bounds__(256) void gemm_mfma_kernel(const float* __restrict__ x,
                                                        const unsigned short* __restrict__ wTg,
                                                        const float* __restrict__ dinv,
                                                        unsigned short* __restrict__ y) {
  __shared__ unsigned short xs[64 * 136];   // 17.4 KB
  __shared__ unsigned short wls[128 * 136]; // 34.8 KB
  int tid = threadIdx.x;
  int row0 = blockIdx.x * 64;
  {  // stage W^T (bf16, coalesced)
    int c = tid >> 1, h = tid & 1;
    const uint4* src = (const uint4*)(wTg + c * D + h * 64);
    uint4* dst = (uint4*)(wls + c * 136 + h * 64);
#pragma unroll
    for (int i = 0; i < 8; i++) dst[i] = src[i];
  }
  {  // stage x rows -> bf16
    int rx = tid >> 2, q = tid & 3;
    int r = row0 + rx;
    if (r > N_NODES - 1) r = N_NODES - 1;
    const float4* src = (const float4*)(x + (size_t)r * D + q * 32);
    uint4* dst = (uint4*)(xs + rx * 136 + q * 32);
#pragma unroll
    for (int i = 0; i < 4; i++) {
      float4 fa = src[2 * i], fb = src[2 * i + 1];
      uint4 p;
      p.x = (unsigned)f2bf(fa.x) | ((unsigned)f2bf(fa.y) << 16);
      p.y = (unsigned)f2bf(fa.z) | ((unsigned)f2bf(fa.w) << 16);
      p.z = (unsigned)f2bf(fb.x) | ((unsigned)f2bf(fb.y) << 16);
      p.w = (unsigned)f2bf(fb.z) | ((unsigned)f2bf(fb.w) << 16);
      dst[i] = p;
    }
  }
  __syncthreads();
  int w = tid >> 6, l = tid & 63;
  int g = l >> 4, ln = l & 15;
  bf16x8 af[4];
#pragma unroll
  for (int kt = 0; kt < 4; kt++)
    af[kt] = *(const bf16x8*)(xs + (w * 16 + ln) * 136 + kt * 32 + g * 8);
  int rbase = row0 + w * 16 + 4 * g;
  float dv[4];
#pragma unroll
  for (int j = 0; j < 4; j++) {
    int r = rbase + j;
    dv[j] = dinv[r < N_NODES ? r : N_NODES - 1];
  }
#pragma unroll
  for (int ct = 0; ct < 8; ct++) {
    f32x4 acc = {0.f, 0.f, 0.f, 0.f};
#pragma unroll
    for (int kt = 0; kt < 4; kt++) {
      bf16x8 bf = *(const bf16x8*)(wls + (ct * 16 + ln) * 136 + kt * 32 + g * 8);
      acc = __builtin_amdgcn_mfma_f32_16x16x32_bf16(af[kt], bf, acc, 0, 0, 0);
    }
#pragma unroll
    for (int j = 0; j < 4; j++) {
      int r = rbase + j;
      if (r < N_NODES) y[(size_t)r * D + ct * 16 + ln] = f2bf(dv[j] * acc[j]);
    }
  }
}

// One wave per node; quarter-waves: 4 edges per load inst, uint4 (8 dims)/lane,
// 16 edges in flight. Fold quarters with shfl_xor(16/32); LN reduce over 16 lanes.
__global__ __launch_bounds__(256) void agg_ln_kernel(
    const unsigned short* __restrict__ y, const unsigned int* __restrict__ csr,
    const int* __restrict__ start, const int* __restrict__ cnt,
    const float* __restrict__ dinv, const float* __restrict__ bias,
    const float* __restrict__ gamma, const float* __restrict__ beta,
    float* __restrict__ out) {
  int wid = threadIdx.x >> 6, lane = threadIdx.x & 63;
  int node = blockIdx.x * 4 + wid;
  if (node >= N_NODES) return;
  int q = lane >> 4, hl = lane & 15;
  int s = start[node];
  int n = cnt[node];
  float a0 = 0.f, a1 = 0.f, a2 = 0.f, a3 = 0.f, a4 = 0.f, a5 = 0.f, a6 = 0.f, a7 = 0.f;
  const unsigned short* yq = y + hl * 8;
#define ACC(V)                                       \
  a0 += __uint_as_float((V).x << 16);                \
  a1 += __uint_as_float((V).x & 0xFFFF0000u);        \
  a2 += __uint_as_float((V).y << 16);                \
  a3 += __uint_as_float((V).y & 0xFFFF0000u);        \
  a4 += __uint_as_float((V).z << 16);                \
  a5 += __uint_as_float((V).z & 0xFFFF0000u);        \
  a6 += __uint_as_float((V).w << 16);                \
  a7 += __uint_as_float((V).w & 0xFFFF0000u);
  for (int j = 0; j < n; j += 64) {
    int m = n - j;
    if (m > 64) m = 64;
    int cj = (j + lane < n) ? (int)csr[s + j + lane] : 0;
    int t = 0;
    for (; t + 15 < m; t += 16) {  // 4 loads = 16 edges in flight
      int e0 = __shfl(cj, t + q);
      int e1 = __shfl(cj, t + 4 + q);
      int e2 = __shfl(cj, t + 8 + q);
      int e3 = __shfl(cj, t + 12 + q);
      uint4 v0 = *(const uint4*)(yq + (size_t)e0 * D);
      uint4 v1 = *(const uint4*)(yq + (size_t)e1 * D);
      uint4 v2 = *(const uint4*)(yq + (size_t)e2 * D);
      uint4 v3 = *(const uint4*)(yq + (size_t)e3 * D);
      ACC(v0) ACC(v1) ACC(v2) ACC(v3)
    }
    for (; t + 3 < m; t += 4) {
      int e0 = __shfl(cj, t + q);
      uint4 v0 = *(const uint4*)(yq + (size_t)e0 * D);
      ACC(v0)
    }
    int rem = m - t;
    if (rem > 0) {  // 1-3 tail edges: quarters < rem participate
      int sl = t + q;
      if (sl > m - 1) sl = m - 1;
      int e0 = __shfl(cj, sl);
      if (q < rem) {
        uint4 v0 = *(const uint4*)(yq + (size_t)e0 * D);
        ACC(v0)
      }
    }
  }
#define FOLD(A)            \
  A += __shfl_xor(A, 16);  \
  A += __shfl_xor(A, 32);
  FOLD(a0) FOLD(a1) FOLD(a2) FOLD(a3) FOLD(a4) FOLD(a5) FOLD(a6) FOLD(a7)
  // self-loop (all lanes add identical full value; quarters stay consistent)
  uint4 sv = *(const uint4*)(yq + (size_t)node * D);
  ACC(sv)
  float di = dinv[node];
  float4 bi0 = *(const float4*)(bias + hl * 8);
  float4 bi1 = *(const float4*)(bias + hl * 8 + 4);
  float v0 = fmaf(di, a0, bi0.x), v1 = fmaf(di, a1, bi0.y);
  float v2 = fmaf(di, a2, bi0.z), v3 = fmaf(di, a3, bi0.w);
  float v4 = fmaf(di, a4, bi1.x), v5 = fmaf(di, a5, bi1.y);
  float v6 = fmaf(di, a6, bi1.z), v7 = fmaf(di, a7, bi1.w);
  float sum = ((v0 + v1) + (v2 + v3)) + ((v4 + v5) + (v6 + v7));
#pragma unroll
  for (int msk = 1; msk <= 8; msk <<= 1) sum += __shfl_xor(sum, msk);
  float mu = sum * (1.0f / 128.0f);
  float d0 = v0 - mu, d1 = v1 - mu, d2 = v2 - mu, d3 = v3 - mu;
  float d4 = v4 - mu, d5 = v5 - mu, d6 = v6 - mu, d7 = v7 - mu;
  float sq = ((d0 * d0 + d1 * d1) + (d2 * d2 + d3 * d3)) +
             ((d4 * d4 + d5 * d5) + (d6 * d6 + d7 * d7));
#pragma unroll
  for (int msk = 1; msk <= 8; msk <<= 1) sq += __shfl_xor(sq, msk);
  float rstd = rsqrtf(sq * (1.0f / 128.0f) + 1e-5f);
  if (q == 0) {
    float4 ga0 = *(const float4*)(gamma + hl * 8);
    float4 ga1 = *(const float4*)(gamma + hl * 8 + 4);
    float4 be0 = *(const float4*)(beta + hl * 8);
    float4 be1 = *(const float4*)(beta + hl * 8 + 4);
    float4 o0, o1;
    o0.x = fmaxf(fmaf(d0 * rstd, ga0.x, be0.x), 0.0f);
    o0.y = fmaxf(fmaf(d1 * rstd, ga0.y, be0.y), 0.0f);
    o0.z = fmaxf(fmaf(d2 * rstd, ga0.z, be0.z), 0.0f);
    o0.w = fmaxf(fmaf(d3 * rstd, ga0.w, be0.w), 0.0f);
    o1.x = fmaxf(fmaf(d4 * rstd, ga1.x, be1.x), 0.0f);
    o1.y = fmaxf(fmaf(d5 * rstd, ga1.y, be1.y), 0.0f);
    o1.z = fmaxf(fmaf(d6 * rstd, ga1.z, be1.z), 0.0f);
    o1.w = fmaxf(fmaf(d7 * rstd, ga1.w, be1.w), 0.0f);
    *(float4*)(out + (size_t)node * D + hl * 8) = o0;
    *(float4*)(out + (size_t)node * D + hl * 8 + 4) = o1;
  }
#undef ACC
#undef FOLD
}

extern "C" void kernel_launch(void* const* d_in, const int* in_sizes, int n_in,
                              void* d_out, int out_size, void* d_ws, size_t ws_size,
                              hipStream_t stream) {
  const float* x = (const float*)d_in[0];
  const void* edges = d_in[1];
  const float* W = (const float*)d_in[2];
  const float* b = (const float*)d_in[3];
  const float* gamma = (const float*)d_in[4];
  const float* beta = (const float*)d_in[5];
  float* out = (float*)d_out;

  char* w = (char*)d_ws;
  size_t off = 0;
  auto take = [&](size_t bytes) {
    size_t r = off;
    off += (bytes + 255) & ~(size_t)255;
    return r;
  };
  int* flag = (int*)(w + take(256));
  int* gcur = (int*)(w + take((size_t)NB * 4));
  int* cnt = (int*)(w + take((size_t)N_NODES * 4));
  int* start = (int*)(w + take((size_t)N_NODES * 4));
  float* dinv = (float*)(w + take((size_t)N_NODES * 4));
  unsigned short* wTg = (unsigned short*)(w + take((size_t)D * D * 2));     // 32 KB
  unsigned int* bstore = (unsigned int*)(w + take((size_t)NB * BCAP * 4));  // 16 MB
  unsigned short* y = (unsigned short*)(w + take((size_t)N_NODES * D * 2)); // 25.6 MB

  detect_kernel<<<1, 256, 0, stream>>>((const int*)edges, flag);
  hipMemsetAsync(gcur, 0, (size_t)NB * 4, stream);
  prep_w_kernel<<<1, 256, 0, stream>>>(W, wTg);
  partition_kernel<<<768, 256, 0, stream>>>(edges, flag, gcur, bstore);
  bucket_kernel<<<NB, 256, 0, stream>>>(gcur, bstore, cnt, start, dinv);
  gemm_mfma_kernel<<<(N_NODES + 63) / 64, 256, 0, stream>>>(x, wTg, dinv, y);
  agg_ln_kernel<<<(N_NODES + 3) / 4, 256, 0, stream>>>(y, bstore, start, cnt, dinv, b, gamma,
                                                       beta, out);
}